// Round 11
// baseline (360.544 us; speedup 1.0000x reference)
//
#include <hip/hip_runtime.h>
#include <hip/hip_bf16.h>

// MHA forward, round 17 (= round 16 resubmitted; bench infra failed, no data).
// r13/r14/r15 post-mortem: LDS-, VALU-, and barrier-cuts all neutral ->
// limiter is the per-kt barrier lockstep (vmcnt/lgkm drain convoy), not any
// pipe. This round deletes the cause: K/V MFMA fragments are loaded DIRECTLY
// from global in fragment shape (bit-identical registers; kperm folded into
// the row index), so attn_mfma has NO LDS, NO barriers, NO staging. Each wave
// owns 32 q rows (2 subtiles) to halve the L2 read amplification (~1GB
// total, XCD-pinned; L1 absorbs intra-block re-reads). Grid 512.
// All other kernels identical to round 15.
// S=2048 B=2 E=1024 H=16 D=64. scale folded into Q (exp2).
// ws (48.3 MB): xb | qwb | owb | Qp | Kp | Vt | wab | rl | flag
// d_out: out[S,B,E] fp32 (4194304) then attn_mean[B,S,S] fp32 (8388608).

#define Sq 2048
#define Bb 2
#define Ee 1024
#define Hh 16
#define Dd 64
#define LOG2E 1.4426950408889634f
#define QSCALE 0.18033688011112042f   // 0.125 * log2(e)

typedef __attribute__((ext_vector_type(8))) short bhalf8;   // 8 bf16 (4 VGPRs)
typedef __attribute__((ext_vector_type(4))) float f32x4;

__device__ __forceinline__ void gld16(const __hip_bfloat16* g, __hip_bfloat16* l) {
    __builtin_amdgcn_global_load_lds(
        (const __attribute__((address_space(1))) unsigned int*)g,
        (__attribute__((address_space(3))) unsigned int*)l, 16, 0, 0);
}

// packed bf16 pair via hardware cvt (RNE), lo=a hi=b — single VALU instr
__device__ __forceinline__ int pkbf(float a, float b) {
    int r;
    asm("v_cvt_pk_bf16_f32 %0, %1, %2" : "=v"(r) : "v"(a), "v"(b));
    return r;
}

// slot s (0..511, 16B chunks of a 64x64 bf16 tile, global-linear) -> swizzled
// frag-major LDS elem offset [f|ks][j|nd][quad][lm][8]
__device__ __forceinline__ int tile_off(int s) {
    return ((s >> 2) & 1) * 2048 + (s >> 7) * 512 + (s & 3) * 128 + ((s >> 3) & 15) * 8;
}

// thread t -> staged global slot g: swap lo3<->mid3 bits within the 64-slot
// window so the tile_off(g) write has bank-quad (g>>3)&7 == t&7 (conflict-free
// 8-lane cycle groups). Bijective per window => wave coalescing unchanged.
__device__ __forceinline__ int swz(int t) {
    return (t & ~63) | ((t & 7) << 3) | ((t >> 3) & 7);
}

// ---------------- fused prep: mask scan + fp32->bf16 conversions ----------------
__global__ __launch_bounds__(256) void prep_k(
    const float* __restrict__ x, const float* __restrict__ am,
    const unsigned int* __restrict__ kpm32,
    const float* __restrict__ qkv_w, const float* __restrict__ out_w,
    __hip_bfloat16* __restrict__ xb, __hip_bfloat16* __restrict__ qwb,
    __hip_bfloat16* __restrict__ owb, unsigned int* __restrict__ flag)
{
    const long i = (long)blockIdx.x*256 + threadIdx.x;
    if (i < 1048576) {                       // mask scan (am 1M float4, kpm 1024 u32)
        float4 v = ((const float4*)am)[i];
        bool nz = (v.x != 0.f) | (v.y != 0.f) | (v.z != 0.f) | (v.w != 0.f);
        if (i < 1024) nz |= (kpm32[i] != 0u);
        if (__ballot(nz)) { if ((threadIdx.x & 63) == 0) atomicOr(flag, 1u); }
    } else if (i < 2097152) {                // x conv with [S,B,E]->[B*S][E]
        const long j = i - 1048576;
        const int m = (int)(j >> 8), e4 = (int)(j & 255);
        const int b = m >> 11, s = m & 2047;
        float4 v = ((const float4*)x)[(size_t)(s*Bb + b)*256 + e4];
        uint2 o;
        o.x = (unsigned)pkbf(v.x, v.y);
        o.y = (unsigned)pkbf(v.z, v.w);
        ((uint2*)xb)[(size_t)m*256 + e4] = o;
    } else if (i < 2883584) {                // qkv_w conv (786432 float4)
        const long j = i - 2097152;
        float4 v = ((const float4*)qkv_w)[j];
        uint2 o;
        o.x = (unsigned)pkbf(v.x, v.y);
        o.y = (unsigned)pkbf(v.z, v.w);
        ((uint2*)qwb)[j] = o;
    } else if (i < 3145728) {                // out_w conv (262144 float4)
        const long j = i - 2883584;
        float4 v = ((const float4*)out_w)[j];
        uint2 o;
        o.x = (unsigned)pkbf(v.x, v.y);
        o.y = (unsigned)pkbf(v.z, v.w);
        ((uint2*)owb)[j] = o;
    }
}

// ---------------- GEMM 1: QKV projection, bf16 MFMA, scatter epilogue ----------------
// Q stored pre-scaled by QSCALE.
__global__ __launch_bounds__(256) void gemm_qkv(
    const __hip_bfloat16* __restrict__ A, const __hip_bfloat16* __restrict__ Bw,
    const float* __restrict__ bias,
    __hip_bfloat16* __restrict__ Qp, __hip_bfloat16* __restrict__ Kp,
    __hip_bfloat16* __restrict__ Vt)
{
    __shared__ __align__(16) __hip_bfloat16 As[128*32];
    __shared__ __align__(16) __hip_bfloat16 Bs[128*32];
    const int t = threadIdx.x;
    const int l = t & 63, lm = l & 15, quad = l >> 4;
    const int w = t >> 6;
    const int mw = (w & 1)*64, nw = (w >> 1)*64;
    const int m0 = blockIdx.y*128, n0 = blockIdx.x*128;

    const int srow = t >> 2;              // 0..63
    const int scol = (t & 3)*8;
    const __hip_bfloat16* ag = A  + (size_t)(m0 + srow)*1024 + scol;
    const __hip_bfloat16* bg = Bw + (size_t)(n0 + srow)*1024 + scol;
    __hip_bfloat16* al = As + t*8;
    __hip_bfloat16* bl = Bs + t*8;

    f32x4 acc[4][4] = {};
    for (int k0 = 0; k0 < 1024; k0 += 32) {
        __syncthreads();
        gld16(ag + k0, al);
        gld16(ag + (size_t)64*1024 + k0, al + 2048);
        gld16(bg + k0, bl);
        gld16(bg + (size_t)64*1024 + k0, bl + 2048);
        __syncthreads();
        bhalf8 af[4], bf[4];
#pragma unroll
        for (int i = 0; i < 4; i++) {
            af[i] = *(const bhalf8*)&As[(mw + i*16 + lm)*32 + quad*8];
            bf[i] = *(const bhalf8*)&Bs[(nw + i*16 + lm)*32 + quad*8];
        }
#pragma unroll
        for (int mf = 0; mf < 4; mf++)
#pragma unroll
            for (int nf = 0; nf < 4; nf++)
                acc[mf][nf] = __builtin_amdgcn_mfma_f32_16x16x32_bf16(af[mf], bf[nf], acc[mf][nf], 0,0,0);
    }
#pragma unroll
    for (int nf = 0; nf < 4; nf++) {
        const int n = n0 + nw + nf*16 + lm;
        const float bz = bias[n];
        const int which = n >> 10, hh = (n >> 6) & 15, dd = n & 63;
#pragma unroll
        for (int mf = 0; mf < 4; mf++)
#pragma unroll
            for (int r = 0; r < 4; r++) {
                const int m = m0 + mw + mf*16 + quad*4 + r;
                const int b2 = m >> 11, s2 = m & 2047;
                const float vf = acc[mf][nf][r] + bz;
                if (which == 0)
                    Qp[((size_t)(b2*Hh + hh)*Sq + s2)*Dd + dd] = __float2bfloat16(vf * QSCALE);
                else if (which == 1)
                    Kp[((size_t)(b2*Hh + hh)*Sq + s2)*Dd + dd] = __float2bfloat16(vf);
                else
                    Vt[((size_t)(b2*Hh + hh)*Dd + dd)*Sq + s2] = __float2bfloat16(vf);
            }
    }
}

// ---------------- Attention core: barrier-free, LDS-free, direct fragments ----------------
// grid 512: blk = xcd + 8*qt + 128*grp ; bh = grp*8 + xcd ; qt 0..15.
// Block = 4 independent waves x 32 q rows (su subtiles at q0 and q0+64).
// Per kt: 8 ak + 8 av b128 fragment loads DIRECT from global (bit-identical
// to the old LDS-staged registers; kperm folded into the K row index:
// row = r + 4*(j>>1) + 8*quad + 32*(j&1)). K/V tiles are XCD-L2-resident;
// no LDS, no __syncthreads, waves drift freely.
__global__ __launch_bounds__(256) void attn_mfma(
    const __hip_bfloat16* __restrict__ Qp, const __hip_bfloat16* __restrict__ Kp,
    const __hip_bfloat16* __restrict__ Vt,
    const float* __restrict__ am, const unsigned char* __restrict__ kpm,
    const unsigned int* __restrict__ flag,
    __hip_bfloat16* __restrict__ wa, float* __restrict__ rlbuf)
{
    const int t = threadIdx.x;
    const int w = t >> 6, l = t & 63, lm = l & 15, quad = l >> 4;
    const int blk = blockIdx.x;
    const int xcd = blk & 7;
    const int qt  = (blk >> 3) & 15;
    const int grp = blk >> 7;                  // 0..3
    const int bh  = grp*8 + xcd;
    const int b   = bh >> 4, h = bh & 15;
    const int q0  = qt*128 + w*16;             // subtile su adds su*64
    const bool masked = (flag[0] != 0u);

    const __hip_bfloat16* qbase = Qp + (size_t)bh*Sq*Dd;
    const __hip_bfloat16* kbase = Kp + (size_t)bh*Sq*Dd;
    const __hip_bfloat16* vbase = Vt + (size_t)bh*Dd*Sq;

    // Q as B-operand (pre-scaled), one-time strided loads (2 subtiles x 2 frags)
    bhalf8 bq[2][2];
#pragma unroll
    for (int su = 0; su < 2; su++) {
        const int q = q0 + su*64 + lm;
        bq[su][0] = *(const bhalf8*)(qbase + (size_t)q*Dd + quad*8);
        bq[su][1] = *(const bhalf8*)(qbase + (size_t)q*Dd + quad*8 + 32);
    }

    // K A-frag permuted row indices (kperm folded): ak[j] row within tile
    int krA[4];
#pragma unroll
    for (int j = 0; j < 4; j++)
        krA[j] = (lm & 3) | ((j >> 1) << 2) | ((lm & 12) << 1) | ((j & 1) << 5);
    const __hip_bfloat16* pK = kbase + quad*8;            // + (k0+krA[j])*Dd + f*32
    const __hip_bfloat16* pV = vbase + (size_t)lm*Sq + quad*8;  // + nd*16*Sq + k0 + ks*32

    f32x4 o[2][4] = {};
    float lsum[2] = {0.f, 0.f};

    for (int kt = 0; kt < 32; kt++) {
        const int k0 = kt*64;
        // direct fragment loads (16 independent b128, deep ILP)
        bhalf8 ak[2][4], av[2][4];
#pragma unroll
        for (int f = 0; f < 2; f++)
#pragma unroll
            for (int j = 0; j < 4; j++)
                ak[f][j] = *(const bhalf8*)(pK + (size_t)(k0 + krA[j])*Dd + f*32);
#pragma unroll
        for (int ks = 0; ks < 2; ks++)
#pragma unroll
            for (int nd = 0; nd < 4; nd++)
                av[ks][nd] = *(const bhalf8*)(pV + (size_t)(nd*16)*Sq + k0 + ks*32);

        // S^T = K · Q^T  (K rows permuted via krA)
        f32x4 s[2][4] = {};
        __builtin_amdgcn_s_setprio(1);
#pragma unroll
        for (int f = 0; f < 2; f++)
#pragma unroll
            for (int su = 0; su < 2; su++)
#pragma unroll
                for (int j = 0; j < 4; j++)
                    s[su][j] = __builtin_amdgcn_mfma_f32_16x16x32_bf16(ak[f][j], bq[su][f], s[su][j], 0,0,0);
        __builtin_amdgcn_s_setprio(0);

        // exp2 + pack; s[su][j][r] is key k0 + 32*(j&1) + 8*quad + 4*(j>>1) + r
        int pk[2][4][2];
#pragma unroll
        for (int su = 0; su < 2; su++) {
            const int q = q0 + su*64 + lm;
#pragma unroll
            for (int j = 0; j < 4; j++) {
                float p[4];
#pragma unroll
                for (int r = 0; r < 4; r++) {
                    float sv = s[su][j][r];
                    if (masked) {
                        const int key = k0 + 32*(j & 1) + 8*quad + 4*(j >> 1) + r;
                        const float km = kpm[b*Sq + key] ? -1e30f : 0.0f;
                        sv += (am[(size_t)q*Sq + key] + km) * LOG2E;
                    }
                    p[r] = exp2f(sv);
                }
                lsum[su] += (p[0]+p[1]) + (p[2]+p[3]);
                pk[su][j][0] = pkbf(p[0], p[1]);
                pk[su][j][1] = pkbf(p[2], p[3]);
            }
        }

        // PV: O^T += V^T · P^T — P^T B-frag lane-local: {pk[su][ks], pk[su][ks+2]}
        __builtin_amdgcn_s_setprio(1);
#pragma unroll
        for (int ks = 0; ks < 2; ks++)
#pragma unroll
            for (int su = 0; su < 2; su++) {
                union { int i[4]; bhalf8 v; } bp;
                bp.i[0] = pk[su][ks][0];
                bp.i[1] = pk[su][ks][1];
                bp.i[2] = pk[su][ks + 2][0];
                bp.i[3] = pk[su][ks + 2][1];
#pragma unroll
                for (int nd = 0; nd < 4; nd++)
                    o[su][nd] = __builtin_amdgcn_mfma_f32_16x16x32_bf16(av[ks][nd], bp.v, o[su][nd], 0,0,0);
            }
        __builtin_amdgcn_s_setprio(0);
    }

#pragma unroll
    for (int su = 0; su < 2; su++) {
        const int q = q0 + su*64 + lm;
        float ls = lsum[su];
        ls += __shfl_xor(ls, 16, 64);
        ls += __shfl_xor(ls, 32, 64);
        const float rl = 1.0f / ls;
        if (quad == 0) rlbuf[(size_t)bh*Sq + q] = rl * 0.0625f;   // pre-scaled by 1/H
#pragma unroll
        for (int nd = 0; nd < 4; nd++) {
            uint2 ou;
            ou.x = (unsigned)pkbf(o[su][nd][0] * rl, o[su][nd][1] * rl);
            ou.y = (unsigned)pkbf(o[su][nd][2] * rl, o[su][nd][3] * rl);
            *(uint2*)(wa + ((size_t)b*Sq + q)*Ee + h*Dd + nd*16 + quad*4) = ou;
        }
    }
}

// ---------------- attn_mean: 128q x 64k, double-buffered K, prefetch-early ----------------
// 1024 blocks x 256 threads (4 waves); wave w owns q rows [q0 + w*32, +32).
// 1D grid XCD-pinned: blk&7 -> q0 low bits so the 32 kc-blocks sharing one Q
// slice run consecutively on one XCD. Per h (1 barrier): stage tile h+1 into
// Ks[(h+1)&1] (regs loaded an iteration earlier -> latency hidden under
// compute), issue loads for h+2, compute from Ks[h&1]. Q A-frags direct
// global; rlbuf is pre-scaled by 1/16.
__global__ __launch_bounds__(256) void attn_mean_k(
    const __hip_bfloat16* __restrict__ Qp, const __hip_bfloat16* __restrict__ Kp,
    const float* __restrict__ am, const unsigned char* __restrict__ kpm,
    const unsigned int* __restrict__ flag,
    const float* __restrict__ rlbuf, float* __restrict__ attn_mean)
{
    __shared__ __align__(16) __hip_bfloat16 Ks[2][4096];   // 2 x (64 keys x 64 d)
    const int t = threadIdx.x;
    const int w = t >> 6, l = t & 63, lm = l & 15, quad = l >> 4;
    const int blk = blockIdx.x;
    const int q0idx = (blk & 7) | (((blk >> 8) & 1) << 3);   // 0..15
    const int kc    = ((blk >> 3) & 31) * 64;
    const int b     = (blk >> 9) & 1;
    const int q0    = q0idx * 128;
    const bool masked = (flag[0] != 0u);

    const int g0 = swz(t), g1 = g0 + 256;
    const int off0 = tile_off(g0), off1 = tile_off(g1);
    const int qa = q0 + w*32;                 // wave's 32 q rows

    float macc[2][4][4] = {};
    uint4 kr0, kr1;

    // stage h=0 directly (no readers yet), issue loads for h=1
    {
        const __hip_bfloat16* kg = Kp + ((size_t)(b*Hh)*Sq + kc)*Dd;
        uint4 a0 = *(const uint4*)(kg + (size_t)g0*8);
        uint4 a1 = *(const uint4*)(kg + (size_t)g1*8);
        *(uint4*)&Ks[0][off0] = a0;
        *(uint4*)&Ks[0][off1] = a1;
        const __hip_bfloat16* kg1 = kg + (size_t)Sq*Dd;
        kr0 = *(const uint4*)(kg1 + (size_t)g0*8);
        kr1 = *(const uint4*)(kg1 + (size_t)g1*8);
    }

    for (int h = 0; h < Hh; h++) {
        __syncthreads();                      // Ks[h&1] visible; prev readers done
        if (h < Hh - 1) {                     // stage tile h+1 (regs already loaded)
            *(uint4*)&Ks[(h + 1) & 1][off0] = kr0;
            *(uint4*)&Ks[(h + 1) & 1][off1] = kr1;
            if (h < Hh - 2) {                 // issue loads for h+2 (hidden under compute)
                const __hip_bfloat16* kn = Kp + ((size_t)(b*Hh + h + 2)*Sq + kc)*Dd;
                kr0 = *(const uint4*)(kn + (size_t)g0*8);
                kr1 = *(const uint4*)(kn + (size_t)g1*8);
            }
        }

        const size_t base = (size_t)(b*Hh + h)*Sq;
        const __hip_bfloat16* Kc = Ks[h & 1];
#pragma unroll
        for (int su = 0; su < 2; su++) {
            const int qrow = qa + su*16;
            const __hip_bfloat16* qg = Qp + (base + qrow + lm)*Dd + quad*8;
            f32x4 s[4] = {};
#pragma unroll
            for (int f = 0; f < 2; f++) {
                bhalf8 aq = *(const bhalf8*)(qg + f*32);
#pragma unroll
                for (int j = 0; j < 4; j++) {
                    bhalf8 bk = *(const bhalf8*)&Kc[f*2048 + j*512 + l*8];
                    s[j] = __builtin_amdgcn_mfma_f32_16x16x32_bf16(aq, bk, s[j], 0,0,0);
                }
            }
            const f32x4 rl4 = *(const f32x4*)(rlbuf + base + qrow + quad*4);
#pragma unroll
            for (int j = 0; j < 4; j++)
#pragma unroll
                for (int r = 0; r < 4; r++) {
                    float sv = s[j][r];
                    if (masked) {
                        const int key = kc + j*16 + lm;
                        const float km = kpm[b*Sq + key] ? -1e30f : 0.0f;
                        sv += (am[(size_t)(qrow + quad*4 + r)*Sq + key] + km) * LOG2E;
                    }
                    macc[su][j][r] += exp2f(sv) * rl4[r];   // rl4 pre-scaled by 1/16
                }
        }
    }

#pragma unroll
    for (int su = 0; su < 2; su++)
#pragma unroll
        for (int j = 0; j < 4; j++)
#pragma unroll
            for (int r = 0; r < 4; r++)
                attn_mean[((size_t)b*Sq + qa + su*16 + quad*4 + r)*Sq + kc + j*16 + lm] =
                    macc[su][j][r];
}

// ---------------- GEMM 2: output projection, bf16 MFMA ----------------
__global__ __launch_bounds__(256) void gemm_out(
    const __hip_bfloat16* __restrict__ A, const __hip_bfloat16* __restrict__ Bw,
    const float* __restrict__ bias, float* __restrict__ outp)
{
    __shared__ __align__(16) __hip_bfloat16 As[128*32];
    __shared__ __align__(16) __hip_bfloat16 Bs[128*32];
    const int t = threadIdx.x;
    const int l = t & 63, lm = l & 15, quad = l >> 4;
    const int w = t >> 6;
    const int mw = (w & 1)*64, nw = (w >> 1)*64;
    const int m0 = blockIdx.y*128, n0 = blockIdx.x*128;

    const int srow = t >> 2;
    const int scol = (t & 3)*8;
    const __hip_bfloat16* ag = A  + (size_t)(m0 + srow)*1024 + scol;
    const __hip_bfloat16* bg = Bw + (size_t)(n0 + srow)*1024 + scol;
    __hip_bfloat16* al = As + t*8;
    __hip_bfloat16* bl = Bs + t*8;

    f32x4 acc[4][4] = {};
    for (int k0 = 0; k0 < 1024; k0 += 32) {
        __syncthreads();
        gld16(ag + k0, al);
        gld16(ag + (size_t)64*1024 + k0, al + 2048);
        gld16(bg + k0, bl);
        gld16(bg + (size_t)64*1024 + k0, bl + 2048);
        __syncthreads();
        bhalf8 af[4], bf[4];
#pragma unroll
        for (int i = 0; i < 4; i++) {
            af[i] = *(const bhalf8*)&As[(mw + i*16 + lm)*32 + quad*8];
            bf[i] = *(const bhalf8*)&Bs[(nw + i*16 + lm)*32 + quad*8];
        }
#pragma unroll
        for (int mf = 0; mf < 4; mf++)
#pragma unroll
            for (int nf = 0; nf < 4; nf++)
                acc[mf][nf] = __builtin_amdgcn_mfma_f32_16x16x32_bf16(af[mf], bf[nf], acc[mf][nf], 0,0,0);
    }
#pragma unroll
    for (int nf = 0; nf < 4; nf++) {
        const int n = n0 + nw + nf*16 + lm;
        const float bz = bias[n];
#pragma unroll
        for (int mf = 0; mf < 4; mf++)
#pragma unroll
            for (int r = 0; r < 4; r++) {
                const int m = m0 + mw + mf*16 + quad*4 + r;
                const int b2 = m >> 11, s2 = m & 2047;
                outp[((size_t)s2*Bb + b2)*Ee + n] = acc[mf][nf][r] + bz;
            }
    }
}

extern "C" void kernel_launch(void* const* d_in, const int* in_sizes, int n_in,
                              void* d_out, int out_size, void* d_ws, size_t ws_size,
                              hipStream_t stream) {
    const float*         x         = (const float*)d_in[0];
    const float*         attn_mask = (const float*)d_in[1];
    const unsigned char* kpm       = (const unsigned char*)d_in[2];
    const float*         qkv_w     = (const float*)d_in[3];
    const float*         qkv_b     = (const float*)d_in[4];
    const float*         out_w     = (const float*)d_in[5];
    const float*         out_b     = (const float*)d_in[6];

    float* outp      = (float*)d_out;
    float* attn_mean = outp + 4194304;          // S*B*E

    __hip_bfloat16* xb  = (__hip_bfloat16*)d_ws;     // 8 MB
    __hip_bfloat16* qwb = xb  + 4194304;             // 6 MB
    __hip_bfloat16* owb = qwb + 3145728;             // 2 MB
    __hip_bfloat16* Qp  = owb + 1048576;             // 8 MB (pre-scaled by QSCALE)
    __hip_bfloat16* Kp  = Qp  + 4194304;             // 8 MB
    __hip_bfloat16* Vt  = Kp  + 4194304;             // 8 MB (transposed [B,H,D,S])
    __hip_bfloat16* wab = Vt  + 4194304;             // 8 MB
    float* rlbuf        = (float*)(wab + 4194304);   // 256 KB (stores rl/16)
    unsigned int* flag  = (unsigned int*)(rlbuf + 65536);

    hipMemsetAsync(flag, 0, sizeof(unsigned int), stream);
    prep_k<<<12288, 256, 0, stream>>>(x, attn_mask, (const unsigned int*)kpm,
                                      qkv_w, out_w, xb, qwb, owb, flag);
    gemm_qkv<<<dim3(24, 32), 256, 0, stream>>>(xb, qwb, qkv_b, Qp, Kp, Vt);
    attn_mfma<<<dim3(512), 256, 0, stream>>>(Qp, Kp, Vt, attn_mask, kpm, flag, wab, rlbuf);
    attn_mean_k<<<dim3(1024), 256, 0, stream>>>(Qp, Kp, attn_mask, kpm, flag, rlbuf, attn_mean);
    gemm_out<<<dim3(8, 32), 256, 0, stream>>>(wab, owb, out_b, outp);
}

// Round 12
// 308.110 us; speedup vs baseline: 1.1702x; 1.1702x over previous
//
#include <hip/hip_runtime.h>
#include <hip/hip_bf16.h>

// MHA forward, round 18: revert attn_mfma to r13 optimum (+cvt_pk only) and
// fuse the independent tail kernels (attn_mean + gemm_out) into ONE dispatch.
// r16/r17 post-mortem: direct-global fragments = 133us (load-latency bound;
// L1 hit ~200cy vs LDS ~12cy, 2 waves/SIMD can't cover) -> staged r13
// structure (82.6us) is the local optimum. r15's dbuf+setprio bundle was
// slightly negative; keep only hw v_cvt_pk_bf16_f32 and rl/16 folding.
// tail_k: blocks 0..255 = gemm_out, 256..1279 = attn_mean (both 16KB LDS,
// shared buffer); grid 1280 = 5 blocks/CU, overlapping the two independent
// kernels instead of serializing them (~15-20us).
// S=2048 B=2 E=1024 H=16 D=64. scale folded into Q (exp2).
// ws (48.3 MB): xb | qwb | owb | Qp | Kp | Vt | wab | rl | flag
// d_out: out[S,B,E] fp32 (4194304) then attn_mean[B,S,S] fp32 (8388608).

#define Sq 2048
#define Bb 2
#define Ee 1024
#define Hh 16
#define Dd 64
#define LOG2E 1.4426950408889634f
#define QSCALE 0.18033688011112042f   // 0.125 * log2(e)

typedef __attribute__((ext_vector_type(8))) short bhalf8;   // 8 bf16 (4 VGPRs)
typedef __attribute__((ext_vector_type(4))) float f32x4;

__device__ __forceinline__ void gld16(const __hip_bfloat16* g, __hip_bfloat16* l) {
    __builtin_amdgcn_global_load_lds(
        (const __attribute__((address_space(1))) unsigned int*)g,
        (__attribute__((address_space(3))) unsigned int*)l, 16, 0, 0);
}

// packed bf16 pair via hardware cvt (RNE), lo=a hi=b — single VALU instr
__device__ __forceinline__ int pkbf(float a, float b) {
    int r;
    asm("v_cvt_pk_bf16_f32 %0, %1, %2" : "=v"(r) : "v"(a), "v"(b));
    return r;
}

// slot s (0..511, 16B chunks of a 64x64 bf16 tile, global-linear) -> swizzled
// frag-major LDS elem offset [f|ks][j|nd][quad][lm][8]
__device__ __forceinline__ int tile_off(int s) {
    return ((s >> 2) & 1) * 2048 + (s >> 7) * 512 + (s & 3) * 128 + ((s >> 3) & 15) * 8;
}

// thread t -> staged global slot g: swap lo3<->mid3 bits within the 64-slot
// window so the tile_off(g) write has bank-quad (g>>3)&7 == t&7 (conflict-free
// 8-lane cycle groups). Bijective per window => wave coalescing unchanged.
__device__ __forceinline__ int swz(int t) {
    return (t & ~63) | ((t & 7) << 3) | ((t >> 3) & 7);
}

// K row permutation: LDS tile row position p holds global key kperm(p).
// p = j*16 + quad*4 + r  ->  key = 32*(j&1) + 8*quad + 4*(j>>1) + r
// so that the QK^T C-registers directly form the PV B-fragment (no shuffles).
__device__ __forceinline__ int kperm(int p) {
    return (p & 3) | (((p >> 5) & 1) << 2) | ((p & 12) << 1) | (((p >> 4) & 1) << 5);
}

// ---------------- fused prep: mask scan + fp32->bf16 conversions ----------------
__global__ __launch_bounds__(256) void prep_k(
    const float* __restrict__ x, const float* __restrict__ am,
    const unsigned int* __restrict__ kpm32,
    const float* __restrict__ qkv_w, const float* __restrict__ out_w,
    __hip_bfloat16* __restrict__ xb, __hip_bfloat16* __restrict__ qwb,
    __hip_bfloat16* __restrict__ owb, unsigned int* __restrict__ flag)
{
    const long i = (long)blockIdx.x*256 + threadIdx.x;
    if (i < 1048576) {                       // mask scan (am 1M float4, kpm 1024 u32)
        float4 v = ((const float4*)am)[i];
        bool nz = (v.x != 0.f) | (v.y != 0.f) | (v.z != 0.f) | (v.w != 0.f);
        if (i < 1024) nz |= (kpm32[i] != 0u);
        if (__ballot(nz)) { if ((threadIdx.x & 63) == 0) atomicOr(flag, 1u); }
    } else if (i < 2097152) {                // x conv with [S,B,E]->[B*S][E]
        const long j = i - 1048576;
        const int m = (int)(j >> 8), e4 = (int)(j & 255);
        const int b = m >> 11, s = m & 2047;
        float4 v = ((const float4*)x)[(size_t)(s*Bb + b)*256 + e4];
        uint2 o;
        o.x = (unsigned)pkbf(v.x, v.y);
        o.y = (unsigned)pkbf(v.z, v.w);
        ((uint2*)xb)[(size_t)m*256 + e4] = o;
    } else if (i < 2883584) {                // qkv_w conv (786432 float4)
        const long j = i - 2097152;
        float4 v = ((const float4*)qkv_w)[j];
        uint2 o;
        o.x = (unsigned)pkbf(v.x, v.y);
        o.y = (unsigned)pkbf(v.z, v.w);
        ((uint2*)qwb)[j] = o;
    } else if (i < 3145728) {                // out_w conv (262144 float4)
        const long j = i - 2883584;
        float4 v = ((const float4*)out_w)[j];
        uint2 o;
        o.x = (unsigned)pkbf(v.x, v.y);
        o.y = (unsigned)pkbf(v.z, v.w);
        ((uint2*)owb)[j] = o;
    }
}

// ---------------- GEMM 1: QKV projection, bf16 MFMA, scatter epilogue ----------------
// Q stored pre-scaled by QSCALE.
__global__ __launch_bounds__(256) void gemm_qkv(
    const __hip_bfloat16* __restrict__ A, const __hip_bfloat16* __restrict__ Bw,
    const float* __restrict__ bias,
    __hip_bfloat16* __restrict__ Qp, __hip_bfloat16* __restrict__ Kp,
    __hip_bfloat16* __restrict__ Vt)
{
    __shared__ __align__(16) __hip_bfloat16 As[128*32];
    __shared__ __align__(16) __hip_bfloat16 Bs[128*32];
    const int t = threadIdx.x;
    const int l = t & 63, lm = l & 15, quad = l >> 4;
    const int w = t >> 6;
    const int mw = (w & 1)*64, nw = (w >> 1)*64;
    const int m0 = blockIdx.y*128, n0 = blockIdx.x*128;

    const int srow = t >> 2;              // 0..63
    const int scol = (t & 3)*8;
    const __hip_bfloat16* ag = A  + (size_t)(m0 + srow)*1024 + scol;
    const __hip_bfloat16* bg = Bw + (size_t)(n0 + srow)*1024 + scol;
    __hip_bfloat16* al = As + t*8;
    __hip_bfloat16* bl = Bs + t*8;

    f32x4 acc[4][4] = {};
    for (int k0 = 0; k0 < 1024; k0 += 32) {
        __syncthreads();
        gld16(ag + k0, al);
        gld16(ag + (size_t)64*1024 + k0, al + 2048);
        gld16(bg + k0, bl);
        gld16(bg + (size_t)64*1024 + k0, bl + 2048);
        __syncthreads();
        bhalf8 af[4], bf[4];
#pragma unroll
        for (int i = 0; i < 4; i++) {
            af[i] = *(const bhalf8*)&As[(mw + i*16 + lm)*32 + quad*8];
            bf[i] = *(const bhalf8*)&Bs[(nw + i*16 + lm)*32 + quad*8];
        }
#pragma unroll
        for (int mf = 0; mf < 4; mf++)
#pragma unroll
            for (int nf = 0; nf < 4; nf++)
                acc[mf][nf] = __builtin_amdgcn_mfma_f32_16x16x32_bf16(af[mf], bf[nf], acc[mf][nf], 0,0,0);
    }
#pragma unroll
    for (int nf = 0; nf < 4; nf++) {
        const int n = n0 + nw + nf*16 + lm;
        const float bz = bias[n];
        const int which = n >> 10, hh = (n >> 6) & 15, dd = n & 63;
#pragma unroll
        for (int mf = 0; mf < 4; mf++)
#pragma unroll
            for (int r = 0; r < 4; r++) {
                const int m = m0 + mw + mf*16 + quad*4 + r;
                const int b2 = m >> 11, s2 = m & 2047;
                const float vf = acc[mf][nf][r] + bz;
                if (which == 0)
                    Qp[((size_t)(b2*Hh + hh)*Sq + s2)*Dd + dd] = __float2bfloat16(vf * QSCALE);
                else if (which == 1)
                    Kp[((size_t)(b2*Hh + hh)*Sq + s2)*Dd + dd] = __float2bfloat16(vf);
                else
                    Vt[((size_t)(b2*Hh + hh)*Dd + dd)*Sq + s2] = __float2bfloat16(vf);
            }
    }
}

// ---------------- Attention core: r13 structure + hw cvt_pk ----------------
// blk = xcd + 8*qt + 256*grp ; bh = grp*8 + xcd. Block = 4 waves x 16 q rows.
// Per kt: K tile (8KB) + V^T tile (8KB) staged into swizzled frag-major LDS.
// K rows permuted at the GLOBAL source (kperm) so QK^T C-regs form the PV
// B-fragment; thread->slot swz makes the staging writes bank-conflict-free.
__global__ __launch_bounds__(256, 4) void attn_mfma(
    const __hip_bfloat16* __restrict__ Qp, const __hip_bfloat16* __restrict__ Kp,
    const __hip_bfloat16* __restrict__ Vt,
    const float* __restrict__ am, const unsigned char* __restrict__ kpm,
    const unsigned int* __restrict__ flag,
    __hip_bfloat16* __restrict__ wa, float* __restrict__ rlbuf)
{
    __shared__ __align__(16) __hip_bfloat16 Ks[4096];
    __shared__ __align__(16) __hip_bfloat16 Vs[4096];
    const int t = threadIdx.x;
    const int w = t >> 6, l = t & 63, lm = l & 15, quad = l >> 4;
    const int blk = blockIdx.x;
    const int xcd = blk & 7;
    const int qt  = (blk >> 3) & 31;
    const int grp = blk >> 8;                  // 0..3
    const int bh  = grp*8 + xcd;
    const int b   = bh >> 4, h = bh & 15;
    const int q   = qt*64 + w*16 + lm;
    const bool masked = (flag[0] != 0u);

    const __hip_bfloat16* qbase = Qp + (size_t)bh*Sq*Dd;
    const __hip_bfloat16* kbase = Kp + (size_t)bh*Sq*Dd;
    const __hip_bfloat16* vbase = Vt + (size_t)bh*Dd*Sq;

    // Q as B-operand (pre-scaled), one-time strided load
    bhalf8 bq[2];
    bq[0] = *(const bhalf8*)(qbase + (size_t)q*Dd + quad*8);
    bq[1] = *(const bhalf8*)(qbase + (size_t)q*Dd + quad*8 + 32);

    f32x4 o[4] = {};
    float lsum = 0.f;

    // staged slots for this thread (swizzled: conflict-free tile_off writes)
    const int g0 = swz(t), g1 = g0 + 256;
    const int off0 = tile_off(g0), off1 = tile_off(g1);
    // permuted global K rows feeding those slots
    const int krow0 = kperm(g0 >> 3);
    const int krow1 = kperm(g1 >> 3);
    const int kcol  = (g0 & 7)*8;
    const int vrow0 = g0 >> 3, vrow1 = g1 >> 3;

    // preload tile 0 staging regs
    uint4 kreg0 = *(const uint4*)(kbase + (size_t)krow0*Dd + kcol);
    uint4 kreg1 = *(const uint4*)(kbase + (size_t)krow1*Dd + kcol);
    uint4 vreg0 = *(const uint4*)(vbase + (size_t)vrow0*Sq + kcol);
    uint4 vreg1 = *(const uint4*)(vbase + (size_t)vrow1*Sq + kcol);

    for (int kt = 0; kt < 32; kt++) {
        __syncthreads();                       // previous tile's readers done
        *(uint4*)&Ks[off0] = kreg0;
        *(uint4*)&Ks[off1] = kreg1;
        *(uint4*)&Vs[off0] = vreg0;
        *(uint4*)&Vs[off1] = vreg1;
        if (kt < 31) {                         // prefetch tile kt+1
            const int kn = (kt + 1)*64;
            kreg0 = *(const uint4*)(kbase + (size_t)(kn + krow0)*Dd + kcol);
            kreg1 = *(const uint4*)(kbase + (size_t)(kn + krow1)*Dd + kcol);
            vreg0 = *(const uint4*)(vbase + (size_t)vrow0*Sq + kn + kcol);
            vreg1 = *(const uint4*)(vbase + (size_t)vrow1*Sq + kn + kcol);
        }
        __syncthreads();                       // tile kt visible

        const int k0 = kt*64;
        // S^T = K · Q^T  (K rows permuted: row p holds key kperm(p))
        f32x4 s[4] = {};
#pragma unroll
        for (int f = 0; f < 2; f++) {
            bhalf8 ak[4];
#pragma unroll
            for (int j = 0; j < 4; j++)
                ak[j] = *(const bhalf8*)&Ks[f*2048 + j*512 + l*8];
#pragma unroll
            for (int j = 0; j < 4; j++)
                s[j] = __builtin_amdgcn_mfma_f32_16x16x32_bf16(ak[j], bq[f], s[j], 0,0,0);
        }

        // exp2 + pack; s[j][r] is key k0 + 32*(j&1) + 8*quad + 4*(j>>1) + r
        int pk[4][2];
#pragma unroll
        for (int j = 0; j < 4; j++) {
            float p[4];
#pragma unroll
            for (int r = 0; r < 4; r++) {
                float sv = s[j][r];
                if (masked) {
                    const int key = k0 + 32*(j & 1) + 8*quad + 4*(j >> 1) + r;
                    const float km = kpm[b*Sq + key] ? -1e30f : 0.0f;
                    sv += (am[(size_t)q*Sq + key] + km) * LOG2E;
                }
                p[r] = exp2f(sv);
            }
            lsum += (p[0]+p[1]) + (p[2]+p[3]);
            pk[j][0] = pkbf(p[0], p[1]);
            pk[j][1] = pkbf(p[2], p[3]);
        }

        // PV: O^T += V^T · P^T — P^T B-frag is lane-local by construction:
        // lane needs keys ks*32 + quad*8 + e  ==  {pk[ks], pk[ks+2]}
#pragma unroll
        for (int ks = 0; ks < 2; ks++) {
            union { int i[4]; bhalf8 v; } bp;
            bp.i[0] = pk[ks][0];
            bp.i[1] = pk[ks][1];
            bp.i[2] = pk[ks + 2][0];
            bp.i[3] = pk[ks + 2][1];
            bhalf8 av[4];
#pragma unroll
            for (int nd = 0; nd < 4; nd++)
                av[nd] = *(const bhalf8*)&Vs[ks*2048 + nd*512 + l*8];
#pragma unroll
            for (int nd = 0; nd < 4; nd++)
                o[nd] = __builtin_amdgcn_mfma_f32_16x16x32_bf16(av[nd], bp.v, o[nd], 0,0,0);
        }
    }

    lsum += __shfl_xor(lsum, 16, 64);
    lsum += __shfl_xor(lsum, 32, 64);
    const float rl = 1.0f / lsum;
    if (quad == 0) rlbuf[(size_t)bh*Sq + q] = rl * 0.0625f;   // pre-scaled by 1/H

#pragma unroll
    for (int nd = 0; nd < 4; nd++) {
        uint2 ou;
        ou.x = (unsigned)pkbf(o[nd][0] * rl, o[nd][1] * rl);
        ou.y = (unsigned)pkbf(o[nd][2] * rl, o[nd][3] * rl);
        *(uint2*)(wa + ((size_t)b*Sq + q)*Ee + h*Dd + nd*16 + quad*4) = ou;
    }
}

// ---------------- fused tail: gemm_out (blocks 0..255) + attn_mean (256..1279) ----------------
// Both bodies use exactly 16KB LDS (shared buffer). gemm_out blocks launch
// first and backfill CUs while the longer attn_mean population runs ->
// overlaps two previously-serialized independent kernels. 1280 blocks = 5/CU.
__global__ __launch_bounds__(256) void tail_k(
    const __hip_bfloat16* __restrict__ Qp, const __hip_bfloat16* __restrict__ Kp,
    const float* __restrict__ am, const unsigned char* __restrict__ kpm,
    const unsigned int* __restrict__ flag,
    const float* __restrict__ rlbuf, float* __restrict__ attn_mean,
    const __hip_bfloat16* __restrict__ A, const __hip_bfloat16* __restrict__ Bw,
    const float* __restrict__ bias, float* __restrict__ outp)
{
    __shared__ __align__(16) __hip_bfloat16 sh[8192];   // 16KB, shared by both roles
    const int t = threadIdx.x;
    const int l = t & 63, lm = l & 15, quad = l >> 4;
    const int w = t >> 6;

    if (blockIdx.x < 256) {
        // ---------------- gemm_out role ----------------
        __hip_bfloat16* As = sh;
        __hip_bfloat16* Bs = sh + 4096;
        const int mw = (w & 1)*64, nw = (w >> 1)*64;
        const int n0 = (blockIdx.x & 7)*128, m0 = (blockIdx.x >> 3)*128;

        const int srow = t >> 2;
        const int scol = (t & 3)*8;
        const __hip_bfloat16* ag = A  + (size_t)(m0 + srow)*1024 + scol;
        const __hip_bfloat16* bg = Bw + (size_t)(n0 + srow)*1024 + scol;
        __hip_bfloat16* al = As + t*8;
        __hip_bfloat16* bl = Bs + t*8;

        f32x4 acc[4][4] = {};
        for (int k0 = 0; k0 < 1024; k0 += 32) {
            __syncthreads();
            gld16(ag + k0, al);
            gld16(ag + (size_t)64*1024 + k0, al + 2048);
            gld16(bg + k0, bl);
            gld16(bg + (size_t)64*1024 + k0, bl + 2048);
            __syncthreads();
            bhalf8 af[4], bf[4];
#pragma unroll
            for (int i = 0; i < 4; i++) {
                af[i] = *(const bhalf8*)&As[(mw + i*16 + lm)*32 + quad*8];
                bf[i] = *(const bhalf8*)&Bs[(nw + i*16 + lm)*32 + quad*8];
            }
#pragma unroll
            for (int mf = 0; mf < 4; mf++)
#pragma unroll
                for (int nf = 0; nf < 4; nf++)
                    acc[mf][nf] = __builtin_amdgcn_mfma_f32_16x16x32_bf16(af[mf], bf[nf], acc[mf][nf], 0,0,0);
        }
#pragma unroll
        for (int nf = 0; nf < 4; nf++) {
            const int n = n0 + nw + nf*16 + lm;
            const float bz = bias[n];
#pragma unroll
            for (int mf = 0; mf < 4; mf++)
#pragma unroll
                for (int r = 0; r < 4; r++) {
                    const int m = m0 + mw + mf*16 + quad*4 + r;
                    const int b2 = m >> 11, s2 = m & 2047;
                    outp[((size_t)s2*Bb + b2)*Ee + n] = acc[mf][nf][r] + bz;
                }
        }
        return;
    }

    // ---------------- attn_mean role ----------------
    __hip_bfloat16 (*Ks)[4096] = (__hip_bfloat16(*)[4096])sh;   // 2 x 8KB
    const int blk = blockIdx.x - 256;
    const int q0idx = (blk & 7) | (((blk >> 8) & 1) << 3);   // 0..15
    const int kc    = ((blk >> 3) & 31) * 64;
    const int b     = (blk >> 9) & 1;
    const int q0    = q0idx * 128;
    const bool masked = (flag[0] != 0u);

    const int g0 = swz(t), g1 = g0 + 256;
    const int off0 = tile_off(g0), off1 = tile_off(g1);
    const int qa = q0 + w*32;                 // wave's 32 q rows

    float macc[2][4][4] = {};
    uint4 kr0, kr1;

    // stage h=0 directly (no readers yet), issue loads for h=1
    {
        const __hip_bfloat16* kg = Kp + ((size_t)(b*Hh)*Sq + kc)*Dd;
        uint4 a0 = *(const uint4*)(kg + (size_t)g0*8);
        uint4 a1 = *(const uint4*)(kg + (size_t)g1*8);
        *(uint4*)&Ks[0][off0] = a0;
        *(uint4*)&Ks[0][off1] = a1;
        const __hip_bfloat16* kg1 = kg + (size_t)Sq*Dd;
        kr0 = *(const uint4*)(kg1 + (size_t)g0*8);
        kr1 = *(const uint4*)(kg1 + (size_t)g1*8);
    }

    for (int h = 0; h < Hh; h++) {
        __syncthreads();                      // Ks[h&1] visible; prev readers done
        if (h < Hh - 1) {                     // stage tile h+1 (regs already loaded)
            *(uint4*)&Ks[(h + 1) & 1][off0] = kr0;
            *(uint4*)&Ks[(h + 1) & 1][off1] = kr1;
            if (h < Hh - 2) {                 // issue loads for h+2 (hidden under compute)
                const __hip_bfloat16* kn = Kp + ((size_t)(b*Hh + h + 2)*Sq + kc)*Dd;
                kr0 = *(const uint4*)(kn + (size_t)g0*8);
                kr1 = *(const uint4*)(kn + (size_t)g1*8);
            }
        }

        const size_t base = (size_t)(b*Hh + h)*Sq;
        const __hip_bfloat16* Kc = Ks[h & 1];
#pragma unroll
        for (int su = 0; su < 2; su++) {
            const int qrow = qa + su*16;
            const __hip_bfloat16* qg = Qp + (base + qrow + lm)*Dd + quad*8;
            f32x4 s[4] = {};
#pragma unroll
            for (int f = 0; f < 2; f++) {
                bhalf8 aq = *(const bhalf8*)(qg + f*32);
#pragma unroll
                for (int j = 0; j < 4; j++) {
                    bhalf8 bk = *(const bhalf8*)&Kc[f*2048 + j*512 + l*8];
                    s[j] = __builtin_amdgcn_mfma_f32_16x16x32_bf16(aq, bk, s[j], 0,0,0);
                }
            }
            const f32x4 rl4 = *(const f32x4*)(rlbuf + base + qrow + quad*4);
#pragma unroll
            for (int j = 0; j < 4; j++)
#pragma unroll
                for (int r = 0; r < 4; r++) {
                    float sv = s[j][r];
                    if (masked) {
                        const int key = kc + j*16 + lm;
                        const float km = kpm[b*Sq + key] ? -1e30f : 0.0f;
                        sv += (am[(size_t)(qrow + quad*4 + r)*Sq + key] + km) * LOG2E;
                    }
                    macc[su][j][r] += exp2f(sv) * rl4[r];   // rl4 pre-scaled by 1/16
                }
        }
    }

#pragma unroll
    for (int su = 0; su < 2; su++)
#pragma unroll
        for (int j = 0; j < 4; j++)
#pragma unroll
            for (int r = 0; r < 4; r++)
                attn_mean[((size_t)b*Sq + qa + su*16 + quad*4 + r)*Sq + kc + j*16 + lm] =
                    macc[su][j][r];
}

extern "C" void kernel_launch(void* const* d_in, const int* in_sizes, int n_in,
                              void* d_out, int out_size, void* d_ws, size_t ws_size,
                              hipStream_t stream) {
    const float*         x         = (const float*)d_in[0];
    const float*         attn_mask = (const float*)d_in[1];
    const unsigned char* kpm       = (const unsigned char*)d_in[2];
    const float*         qkv_w     = (const float*)d_in[3];
    const float*         qkv_b     = (const float*)d_in[4];
    const float*         out_w     = (const float*)d_in[5];
    const float*         out_b     = (const float*)d_in[6];

    float* outp      = (float*)d_out;
    float* attn_mean = outp + 4194304;          // S*B*E

    __hip_bfloat16* xb  = (__hip_bfloat16*)d_ws;     // 8 MB
    __hip_bfloat16* qwb = xb  + 4194304;             // 6 MB
    __hip_bfloat16* owb = qwb + 3145728;             // 2 MB
    __hip_bfloat16* Qp  = owb + 1048576;             // 8 MB (pre-scaled by QSCALE)
    __hip_bfloat16* Kp  = Qp  + 4194304;             // 8 MB
    __hip_bfloat16* Vt  = Kp  + 4194304;             // 8 MB (transposed [B,H,D,S])
    __hip_bfloat16* wab = Vt  + 4194304;             // 8 MB
    float* rlbuf        = (float*)(wab + 4194304);   // 256 KB (stores rl/16)
    unsigned int* flag  = (unsigned int*)(rlbuf + 65536);

    hipMemsetAsync(flag, 0, sizeof(unsigned int), stream);
    prep_k<<<12288, 256, 0, stream>>>(x, attn_mask, (const unsigned int*)kpm,
                                      qkv_w, out_w, xb, qwb, owb, flag);
    gemm_qkv<<<dim3(24, 32), 256, 0, stream>>>(xb, qwb, qkv_b, Qp, Kp, Vt);
    attn_mfma<<<dim3(1024), 256, 0, stream>>>(Qp, Kp, Vt, attn_mask, kpm, flag, wab, rlbuf);
    tail_k<<<dim3(1280), 256, 0, stream>>>(Qp, Kp, attn_mask, kpm, flag, rlbuf, attn_mean,
                                           wab, owb, out_b, outp);
}